// Round 11
// baseline (1170.678 us; speedup 1.0000x reference)
//
#include <hip/hip_runtime.h>
#include <math.h>

// Problem constants
#define BB 64
#define LL 24
#define DD 512
#define GG 2560        // 5*H
#define NSTEP 23       // LL-1
#define NBLK 256       // cooperative grid (1 block/CU, proven resident)
#define NTILES 160     // phase-B n-tiles: 5120/32, full-K per tile
#define BARLINE 16

__device__ __forceinline__ float sigm(float x) { return 1.0f / (1.0f + __expf(-x)); }

// ---------------------------------------------------------------------------
// Agent-scope (sc1) relaxed access helpers — cross-XCD coherent, NO cache
// maintenance (R5 lesson: acquire/release fences flush/invalidate L2).
// ---------------------------------------------------------------------------
__device__ __forceinline__ void stf2(float* p, float a, float b) {
    union { float f[2]; unsigned long long u; } x;
    x.f[0] = a; x.f[1] = b;
    __hip_atomic_store((unsigned long long*)p, x.u, __ATOMIC_RELAXED, __HIP_MEMORY_SCOPE_AGENT);
}
__device__ __forceinline__ float2 ldf2(const float* p) {
    union { float f[2]; unsigned long long u; } x;
    x.u = __hip_atomic_load((unsigned long long*)p, __ATOMIC_RELAXED, __HIP_MEMORY_SCOPE_AGENT);
    return make_float2(x.f[0], x.f[1]);
}
__device__ __forceinline__ void stf(float* p, float v) {
    __hip_atomic_store(p, v, __ATOMIC_RELAXED, __HIP_MEMORY_SCOPE_AGENT);
}
__device__ __forceinline__ float ldf(const float* p) {
    return __hip_atomic_load((float*)p, __ATOMIC_RELAXED, __HIP_MEMORY_SCOPE_AGENT);
}
__device__ __forceinline__ void sti(int* p, int v) {
    __hip_atomic_store(p, v, __ATOMIC_RELAXED, __HIP_MEMORY_SCOPE_AGENT);
}
__device__ __forceinline__ int ldi(const int* p) {
    return __hip_atomic_load((int*)p, __ATOMIC_RELAXED, __HIP_MEMORY_SCOPE_AGENT);
}
__device__ __forceinline__ void drain_stores() {
    asm volatile("s_waitcnt vmcnt(0)" ::: "memory");
}

// ---------------------------------------------------------------------------
// R11 sync. bar layout (ints):
//   [0..63]    A-flag words: A-block b plain-stores (i+1) at step i (2 lines,
//              no RMW serialization).
//   [128+j*16] j=0..3: B-done counters (fetch_add), 40 arrivals/line/step.
//   [192+j*16] j=0..3: pre-done counters, 64/line.
// Detection = ONE wave-wide load (+__all). Polls sleep ~0.34us between probes
// starting at the first failed probe (kills arrival-instant read storms).
// ---------------------------------------------------------------------------
__device__ __forceinline__ void waitA(const int* flags, int tgt) {
    if (threadIdx.x < 64) {
        for (;;) {
            int v = ldi(flags + threadIdx.x);
            if (__all(v >= tgt)) break;
            __builtin_amdgcn_s_sleep(8);
        }
    }
    __syncthreads();
}
template <int NL>
__device__ __forceinline__ void waitCnt(const int* base, int tgt) {
    if (threadIdx.x < 64) {
        for (;;) {
            int v = (threadIdx.x < NL) ? ldi(base + threadIdx.x * BARLINE) : tgt;
            if (__all(v >= tgt)) break;
            __builtin_amdgcn_s_sleep(8);
        }
    }
    __syncthreads();
}

__global__ void init_k(int* __restrict__ bar) {
    if (threadIdx.x < 256) bar[threadIdx.x] = 0;
}

// ---------------------------------------------------------------------------
// fp32 GEMM, 64x128 tile (unchanged — verified).
// ---------------------------------------------------------------------------
template <int MODE>
__global__ __launch_bounds__(256) void gemm64(const float* __restrict__ A,
                                              const float* __restrict__ Wt,
                                              const float* __restrict__ bias,
                                              float* __restrict__ O0,
                                              float* __restrict__ O1) {
    __shared__ float As[16][68];
    __shared__ float Bs[16][132];
    const int tid = threadIdx.x;
    const int n0 = blockIdx.x * 128;
    const int m0 = blockIdx.y * 64;
    const int tn = tid & 15;
    const int tm = tid >> 4;

    float acc[4][8];
#pragma unroll
    for (int y = 0; y < 4; ++y)
#pragma unroll
        for (int x = 0; x < 8; ++x) acc[y][x] = 0.f;

    for (int kt = 0; kt < 512; kt += 16) {
        {
            int r = tid >> 2, c4 = tid & 3;
            float4 v = *(const float4*)(A + (size_t)(m0 + r) * DD + kt + c4 * 4);
            As[c4 * 4 + 0][r] = v.x;
            As[c4 * 4 + 1][r] = v.y;
            As[c4 * 4 + 2][r] = v.z;
            As[c4 * 4 + 3][r] = v.w;
        }
#pragma unroll
        for (int ii = 0; ii < 2; ++ii) {
            int idx = tid + ii * 256;
            int r = idx >> 2, c4 = idx & 3;
            int n = n0 + r;
            const float* wrow;
            if constexpr (MODE == 0) {
                wrow = Wt + (size_t)n * DD;
            } else {
                wrow = (n < GG) ? (Wt + (size_t)n * (2 * DD))
                                : (Wt + (size_t)(n - GG) * (2 * DD) + DD);
            }
            float4 v = *(const float4*)(wrow + kt + c4 * 4);
            Bs[c4 * 4 + 0][r] = v.x;
            Bs[c4 * 4 + 1][r] = v.y;
            Bs[c4 * 4 + 2][r] = v.z;
            Bs[c4 * 4 + 3][r] = v.w;
        }
        __syncthreads();
#pragma unroll
        for (int k = 0; k < 16; ++k) {
            float4 a = *(const float4*)&As[k][tm * 4];
            float4 b0 = *(const float4*)&Bs[k][tn * 4];
            float4 b1 = *(const float4*)&Bs[k][64 + tn * 4];
            float av[4] = {a.x, a.y, a.z, a.w};
            float bv[8] = {b0.x, b0.y, b0.z, b0.w, b1.x, b1.y, b1.z, b1.w};
#pragma unroll
            for (int y = 0; y < 4; ++y)
#pragma unroll
                for (int x = 0; x < 8; ++x) acc[y][x] += av[y] * bv[x];
        }
        __syncthreads();
    }

#pragma unroll
    for (int y = 0; y < 4; ++y) {
        const int m = m0 + tm * 4 + y;
#pragma unroll
        for (int g = 0; g < 2; ++g) {
            int n = n0 + g * 64 + tn * 4;
            float4 v;
            v.x = acc[y][g * 4 + 0];
            v.y = acc[y][g * 4 + 1];
            v.z = acc[y][g * 4 + 2];
            v.w = acc[y][g * 4 + 3];
            float* dst;
            if constexpr (MODE == 0) {
                v.x += bias[n + 0];
                v.y += bias[n + 1];
                v.z += bias[n + 2];
                v.w += bias[n + 3];
                dst = (n < DD) ? (O0 + (size_t)m * DD + n) : (O1 + (size_t)m * DD + (n - DD));
            } else {
                dst = (n < GG) ? (O0 + (size_t)m * GG + n) : (O1 + (size_t)m * GG + (n - GG));
            }
            *(float4*)dst = v;
        }
    }
}

// ---------------------------------------------------------------------------
__device__ __forceinline__ float half_dot(const float* __restrict__ ar,
                                          const float* __restrict__ br,
                                          const float* __restrict__ cb,
                                          const float* __restrict__ cl,
                                          const float* __restrict__ cr,
                                          const float* __restrict__ q, int lane) {
    float part = 0.f;
#pragma unroll
    for (int d = lane; d < DD; d += 128) {
        float gi = ar[d] + br[d] + cb[d];
        float gfl = ar[DD + d] + br[DD + d] + cb[DD + d];
        float gfr = ar[2 * DD + d] + br[2 * DD + d] + cb[2 * DD + d];
        float gu = ar[3 * DD + d] + br[3 * DD + d] + cb[3 * DD + d];
        float go = ar[4 * DD + d] + br[4 * DD + d] + cb[4 * DD + d];
        float nc = cl[d] * sigm(gfl + 1.f) + cr[d] * sigm(gfr + 1.f) + tanhf(gu) * sigm(gi);
        part += sigm(go) * tanhf(nc) * q[d];
    }
#pragma unroll
    for (int off = 32; off; off >>= 1) part += __shfl_down(part, off);
    return part;
}

__device__ __forceinline__ void gate2(const float* ar, const float* br,
                                      const float* __restrict__ cb,
                                      const float* __restrict__ cl,
                                      const float* __restrict__ cr, int d,
                                      float nh[2], float nc[2]) {
    float2 A0 = ldf2(ar + d),          B0 = ldf2(br + d);
    float2 A1 = ldf2(ar + DD + d),     B1 = ldf2(br + DD + d);
    float2 A2 = ldf2(ar + 2 * DD + d), B2 = ldf2(br + 2 * DD + d);
    float2 A3 = ldf2(ar + 3 * DD + d), B3 = ldf2(br + 3 * DD + d);
    float2 A4 = ldf2(ar + 4 * DD + d), B4 = ldf2(br + 4 * DD + d);
    float2 C0 = *(const float2*)(cb + d);
    float2 C1 = *(const float2*)(cb + DD + d);
    float2 C2 = *(const float2*)(cb + 2 * DD + d);
    float2 C3 = *(const float2*)(cb + 3 * DD + d);
    float2 C4 = *(const float2*)(cb + 4 * DD + d);
    float2 CL = *(const float2*)(cl + d);
    float2 CR = *(const float2*)(cr + d);
    float gi0 = A0.x + B0.x + C0.x, gi1 = A0.y + B0.y + C0.y;
    float gfl0 = A1.x + B1.x + C1.x, gfl1 = A1.y + B1.y + C1.y;
    float gfr0 = A2.x + B2.x + C2.x, gfr1 = A2.y + B2.y + C2.y;
    float gu0 = A3.x + B3.x + C3.x, gu1 = A3.y + B3.y + C3.y;
    float go0 = A4.x + B4.x + C4.x, go1 = A4.y + B4.y + C4.y;
    nc[0] = CL.x * sigm(gfl0 + 1.f) + CR.x * sigm(gfr0 + 1.f) + tanhf(gu0) * sigm(gi0);
    nc[1] = CL.y * sigm(gfl1 + 1.f) + CR.y * sigm(gfr1 + 1.f) + tanhf(gu1) * sigm(gi1);
    nh[0] = sigm(go0) * tanhf(nc[0]);
    nh[1] = sigm(go1) * tanhf(nc[1]);
}

// ---------------------------------------------------------------------------
// Persistent kernel. R11: phase-B 4x4 microtile on 128 threads (LDS-balanced),
// store-based A-flags + sleepy polls.
// ---------------------------------------------------------------------------
__global__ __launch_bounds__(256, 2) void loop_k(
    const int* __restrict__ length, float* __restrict__ cbuf, float* __restrict__ acache,
    float* __restrict__ bcache, float* __restrict__ hm, float* __restrict__ hout,
    float* __restrict__ scores_g, int* __restrict__ msel, const float* __restrict__ comp_W,
    const float* __restrict__ compb, const float* __restrict__ q, float* __restrict__ out,
    int* __restrict__ bar) {
    __shared__ float As[128][68];   // phase-B A chunk (k-major, row=lane)
    __shared__ float Bs[128][36];   // phase-B W chunk
    __shared__ float red_s[4];
    __shared__ float sc_l[32];
    __shared__ int seq_l[32];
    __shared__ int k_sh;
    __shared__ int msel_s[BB];

    const int tid = threadIdx.x;
    const int bid = blockIdx.x;
    const int b = bid;
    const bool amA = bid < BB;
    const int half = tid >> 7;
    const int lane7 = tid & 127;

    int* Aflag = bar;           // 64 words
    int* Bcnt = bar + 128;      // 4 lines
    int* Pcnt = bar + 192;      // 4 lines

    int maxlen = 0;
    for (int j = 0; j < BB; ++j) maxlen = max(maxlen, length[j]);
    int lenb = 0, kp = 0;
    if (amA) lenb = length[b];

    // phase-B roles: 128 active threads, tile 64x32, microtile 4x4
    const bool bAct = tid < 128;
    const int tm = tid >> 3, tn = tid & 7;        // compute roles (tid<128)
    const int sar = tid & 63, sak = tid >> 6;     // A staging: row=lane, 2 k-slices
    const int swn = tid & 31, swk = tid >> 5;     // W staging: row=lane%32, 4 k-slices
    const float* wrow = nullptr;
    if (bid < NTILES) {
        int n = bid * 32 + swn;
        wrow = (n < GG) ? (comp_W + (size_t)n * (2 * DD))
                        : (comp_W + (size_t)(n - GG) * (2 * DD) + DD);
    }

    // ---- pre-phase: 23x64 initial candidate scores ----
    for (int it = 0; it < 3; ++it) {
        int c = it * (2 * NBLK) + bid * 2 + half;
        bool valid = c < BB * NSTEP;
        float w = 0.f;
        if (valid) {
            int cb_ = c / NSTEP, cp = c % NSTEP;
            w = half_dot(acache + (size_t)(cb_ * LL + cp) * GG,
                         bcache + (size_t)(cb_ * LL + cp + 1) * GG, compb,
                         cbuf + (size_t)(cb_ * LL + cp) * DD,
                         cbuf + (size_t)(cb_ * LL + cp + 1) * DD, q, lane7);
        }
        if ((tid & 63) == 0) red_s[tid >> 6] = w;
        __syncthreads();
        if ((tid == 0 || tid == 128) && valid) {
            int base = (tid >> 6);
            stf(&scores_g[c], red_s[base] + red_s[base + 1]);
        }
        __syncthreads();
    }
    if (tid == 0) {
        drain_stores();
        (void)__hip_atomic_fetch_add(Pcnt + (bid & 3) * BARLINE, 1, __ATOMIC_RELAXED,
                                     __HIP_MEMORY_SCOPE_AGENT);
    }
    if (bid >= NTILES) return;

    if (amA) {
        waitCnt<4>(Pcnt, 64);
        if (tid < NSTEP) sc_l[tid] = ldf(&scores_g[b * NSTEP + tid]);
        if (tid < LL) seq_l[tid] = tid;
    }
    __syncthreads();

    const int imax = min(NSTEP, maxlen - 1);
    for (int i = 0; i < imax; ++i) {
        // ---------------- phase A (blocks 0..63) ----------------
        if (amA) {
            if (i > 0) waitCnt<4>(Bcnt, 40 * i);  // B-done[i-1]
            const int ncand = NSTEP - i;
            if (i > 0 && i < lenb) {
                int p = (tid < 128) ? (kp - 1) : kp;
                bool valid = (p >= 0) && (p < ncand);
                float w = 0.f;
                if (valid) {
                    int sl = seq_l[p], sr = seq_l[p + 1];
                    const float* ar = acache + (size_t)(b * LL + sl) * GG;
                    const float* br = bcache + (size_t)(b * LL + sr) * GG;
                    const float* cl = cbuf + (size_t)(b * LL + sl) * DD;
                    const float* cr = cbuf + (size_t)(b * LL + sr) * DD;
#pragma unroll
                    for (int pass = 0; pass < 2; ++pass) {
                        int d = pass * 256 + lane7 * 2;
                        float nh[2], nc[2];
                        gate2(ar, br, compb, cl, cr, d, nh, nc);
                        float2 Q = *(const float2*)(q + d);
                        w += nh[0] * Q.x + nh[1] * Q.y;
                    }
#pragma unroll
                    for (int off = 32; off; off >>= 1) w += __shfl_down(w, off);
                }
                if ((tid & 63) == 0) red_s[tid >> 6] = w;
                __syncthreads();
                if (tid == 0) {
                    if (kp - 1 >= 0) sc_l[kp - 1] = red_s[0] + red_s[1];
                    if (kp < ncand) sc_l[kp] = red_s[2] + red_s[3];
                }
                __syncthreads();
            }
            if (i + 1 < lenb) {
                if (tid == 0) {
                    const int vmax = lenb - i - 2;
                    int k = 0;
                    float best = sc_l[0];
                    for (int pp = 1; pp <= vmax; ++pp)
                        if (sc_l[pp] > best) { best = sc_l[pp]; k = pp; }
                    k_sh = k;
                }
                __syncthreads();
                const int k = k_sh;
                const int sl = seq_l[k], sr = seq_l[k + 1];
                const float* ar = acache + (size_t)(b * LL + sl) * GG;
                const float* br = bcache + (size_t)(b * LL + sr) * GG;
                const float* cl = cbuf + (size_t)(b * LL + sl) * DD;
                const float* cr = cbuf + (size_t)(b * LL + sr) * DD;
                {
                    const int d = 2 * tid;
                    float nh[2], nc[2];
                    gate2(ar, br, compb, cl, cr, d, nh, nc);
                    *(float2*)(cbuf + (size_t)(b * LL + sl) * DD + d) =
                        make_float2(nc[0], nc[1]);
                    *(float2*)(hout + (size_t)b * DD + d) = make_float2(nh[0], nh[1]);
                    stf2(hm + ((size_t)i * BB + b) * DD + d, nh[0], nh[1]);
                }
                float sv = (tid + 1 < ncand) ? sc_l[tid + 1] : 0.f;
                int qv = (tid + 1 < LL - i) ? seq_l[tid + 1] : 0;
                __syncthreads();
                if (tid >= k + 1 && tid <= ncand - 2) sc_l[tid] = sv;
                if (tid >= k + 1 && tid <= LL - i - 2) seq_l[tid] = qv;
                if (tid == 0) sti(&msel[b], sl);
                kp = k;
            } else {
                const int d = 2 * tid;
                float2 v = *(const float2*)(hout + (size_t)b * DD + d);
                stf2(hm + ((size_t)i * BB + b) * DD + d, v.x, v.y);
            }
            __syncthreads();
            if (tid == 0) { drain_stores(); sti(&Aflag[b], i + 1); }
        }
        // ---------------- phase B (blocks 0..159, 128 active threads) --------
        if (i < imax - 1) {
            float4 rw[8];
            if (bAct) {  // W prefetch: input-stable, legal pre-wait
#pragma unroll
                for (int j = 0; j < 8; ++j) rw[j] = *(const float4*)(wrow + swk * 32 + j * 4);
            }
            waitA(Aflag, i + 1);
            if (tid < BB) msel_s[tid] = ldi(&msel[tid]);
            __syncthreads();
            {
                const float* hmi = hm + (size_t)i * BB * DD;
                const float* arow = hmi + (size_t)sar * DD;
                float acc[4][4];
#pragma unroll
                for (int y = 0; y < 4; ++y)
#pragma unroll
                    for (int x = 0; x < 4; ++x) acc[y][x] = 0.f;
                float4 ra[16];
                if (bAct) {
#pragma unroll
                    for (int j = 0; j < 16; ++j)
                        ra[j] = *(const float4*)(arow + sak * 64 + j * 4);
                }
#pragma unroll 1
                for (int c = 0; c < 4; ++c) {
                    __syncthreads();
                    if (bAct) {
#pragma unroll
                        for (int j = 0; j < 16; ++j) {  // A: 64 rows x 128 k
                            int kl = sak * 64 + j * 4;
                            As[kl + 0][sar] = ra[j].x;
                            As[kl + 1][sar] = ra[j].y;
                            As[kl + 2][sar] = ra[j].z;
                            As[kl + 3][sar] = ra[j].w;
                        }
#pragma unroll
                        for (int j = 0; j < 8; ++j) {   // W: 32 rows x 128 k
                            int kl = swk * 32 + j * 4;
                            Bs[kl + 0][swn] = rw[j].x;
                            Bs[kl + 1][swn] = rw[j].y;
                            Bs[kl + 2][swn] = rw[j].z;
                            Bs[kl + 3][swn] = rw[j].w;
                        }
                        if (c < 3) {
                            int kb = (c + 1) * 128;
#pragma unroll
                            for (int j = 0; j < 16; ++j)
                                ra[j] = *(const float4*)(arow + kb + sak * 64 + j * 4);
#pragma unroll
                            for (int j = 0; j < 8; ++j)
                                rw[j] = *(const float4*)(wrow + kb + swk * 32 + j * 4);
                        }
                    }
                    __syncthreads();
                    if (bAct) {
#pragma unroll 8
                        for (int k = 0; k < 128; ++k) {
                            float4 a = *(const float4*)&As[k][tm * 4];
                            float4 w = *(const float4*)&Bs[k][tn * 4];
                            float av[4] = {a.x, a.y, a.z, a.w};
                            float wv[4] = {w.x, w.y, w.z, w.w};
#pragma unroll
                            for (int y = 0; y < 4; ++y)
#pragma unroll
                                for (int x = 0; x < 4; ++x) acc[y][x] += av[y] * wv[x];
                        }
                    }
                }
                if (bAct) {
                    const int n = bid * 32 + tn * 4;  // whole block in a- or b-range
#pragma unroll
                    for (int y = 0; y < 4; ++y) {
                        int m = tm * 4 + y;
                        size_t row = (size_t)(m * LL + msel_s[m]);
                        float* dst = (n < GG) ? (acache + row * GG + n)
                                              : (bcache + row * GG + (n - GG));
                        stf2(dst + 0, acc[y][0], acc[y][1]);
                        stf2(dst + 2, acc[y][2], acc[y][3]);
                    }
                }
            }
            __syncthreads();
            if (tid == 0) {
                drain_stores();
                (void)__hip_atomic_fetch_add(Bcnt + (bid & 3) * BARLINE, 1, __ATOMIC_RELAXED,
                                             __HIP_MEMORY_SCOPE_AGENT);
            }
        }
    }

    if (amA) {
        const int d = 2 * tid;
        *(float2*)(out + (size_t)b * DD + d) = *(const float2*)(hout + (size_t)b * DD + d);
    }
}

// ---------------------------------------------------------------------------
extern "C" void kernel_launch(void* const* d_in, const int* in_sizes, int n_in, void* d_out,
                              int out_size, void* d_ws, size_t ws_size, hipStream_t stream) {
    const float* inp = (const float*)d_in[0];
    const int* length = (const int*)d_in[1];
    const float* word_W = (const float*)d_in[2];
    const float* word_b = (const float*)d_in[3];
    const float* comp_W = (const float*)d_in[4];
    const float* comp_b = (const float*)d_in[5];
    const float* comp_q = (const float*)d_in[6];
    float* out = (float*)d_out;

    float* ws = (float*)d_ws;
    size_t off = 0;
    float* hbuf = ws + off;   off += (size_t)BB * LL * DD;
    float* cbuf = ws + off;   off += (size_t)BB * LL * DD;
    float* acache = ws + off; off += (size_t)BB * LL * GG;
    float* bcache = ws + off; off += (size_t)BB * LL * GG;
    float* hm = ws + off;     off += (size_t)NSTEP * BB * DD;
    float* hout = ws + off;   off += (size_t)BB * DD;
    float* scores = ws + off; off += 2048;
    int* msel = (int*)(ws + off); off += 64;
    int* bar = (int*)(ws + off);  off += 256;
    (void)ws_size; (void)in_sizes; (void)n_in; (void)out_size;

    init_k<<<1, 256, 0, stream>>>(bar);

    // word projection: h,c = split(inp @ word_W.T + word_b)
    gemm64<0><<<dim3(8, 24), 256, 0, stream>>>(inp, word_W, word_b, hbuf, cbuf);

    // a/b caches for all 1536 items
    gemm64<1><<<dim3(40, 24), 256, 0, stream>>>(hbuf, comp_W, nullptr, acache, bcache);

    // persistent kernel: pre-scores + all merge steps
    const int* a0 = length;
    float* a1 = cbuf; float* a2 = acache; float* a3 = bcache; float* a4 = hm;
    float* a5 = hout; float* a6 = scores; int* a7 = msel;
    const float* a8 = comp_W; const float* a9 = comp_b; const float* a10 = comp_q;
    float* a11 = out; int* a12 = bar;
    void* args[] = {&a0, &a1, &a2, &a3, &a4, &a5, &a6, &a7, &a8, &a9, &a10, &a11, &a12};
    hipError_t err = hipLaunchCooperativeKernel(reinterpret_cast<void*>(loop_k), dim3(NBLK),
                                                dim3(256), args, 0, stream);
    (void)err;
}

// Round 12
// 770.559 us; speedup vs baseline: 1.5193x; 1.5193x over previous
//
#include <hip/hip_runtime.h>
#include <math.h>

// Problem constants
#define BB 64
#define LL 24
#define DD 512
#define GG 2560        // 5*H
#define NSTEP 23       // LL-1
#define NTILES 160     // stepB n-tiles: 5120/32, full-K per tile

__device__ __forceinline__ float sigm(float x) { return 1.0f / (1.0f + __expf(-x)); }

// ---------------------------------------------------------------------------
// fp32 GEMM, 64x128 tile (verified R7-R11). C[m][n] = sum_k A[m][k]*W[n][k].
// MODE 0 = WORD (W 1024x512 row-major, +bias, out h|c split at n=512)
// MODE 1 = AB0  (W = comp_W halves at n=2560)
// ---------------------------------------------------------------------------
template <int MODE>
__global__ __launch_bounds__(256) void gemm64(const float* __restrict__ A,
                                              const float* __restrict__ Wt,
                                              const float* __restrict__ bias,
                                              float* __restrict__ O0,
                                              float* __restrict__ O1) {
    __shared__ float As[16][68];
    __shared__ float Bs[16][132];
    const int tid = threadIdx.x;
    const int n0 = blockIdx.x * 128;
    const int m0 = blockIdx.y * 64;
    const int tn = tid & 15;
    const int tm = tid >> 4;

    float acc[4][8];
#pragma unroll
    for (int y = 0; y < 4; ++y)
#pragma unroll
        for (int x = 0; x < 8; ++x) acc[y][x] = 0.f;

    for (int kt = 0; kt < 512; kt += 16) {
        {
            int r = tid >> 2, c4 = tid & 3;
            float4 v = *(const float4*)(A + (size_t)(m0 + r) * DD + kt + c4 * 4);
            As[c4 * 4 + 0][r] = v.x;
            As[c4 * 4 + 1][r] = v.y;
            As[c4 * 4 + 2][r] = v.z;
            As[c4 * 4 + 3][r] = v.w;
        }
#pragma unroll
        for (int ii = 0; ii < 2; ++ii) {
            int idx = tid + ii * 256;
            int r = idx >> 2, c4 = idx & 3;
            int n = n0 + r;
            const float* wrow;
            if constexpr (MODE == 0) {
                wrow = Wt + (size_t)n * DD;
            } else {
                wrow = (n < GG) ? (Wt + (size_t)n * (2 * DD))
                                : (Wt + (size_t)(n - GG) * (2 * DD) + DD);
            }
            float4 v = *(const float4*)(wrow + kt + c4 * 4);
            Bs[c4 * 4 + 0][r] = v.x;
            Bs[c4 * 4 + 1][r] = v.y;
            Bs[c4 * 4 + 2][r] = v.z;
            Bs[c4 * 4 + 3][r] = v.w;
        }
        __syncthreads();
#pragma unroll
        for (int k = 0; k < 16; ++k) {
            float4 a = *(const float4*)&As[k][tm * 4];
            float4 b0 = *(const float4*)&Bs[k][tn * 4];
            float4 b1 = *(const float4*)&Bs[k][64 + tn * 4];
            float av[4] = {a.x, a.y, a.z, a.w};
            float bv[8] = {b0.x, b0.y, b0.z, b0.w, b1.x, b1.y, b1.z, b1.w};
#pragma unroll
            for (int y = 0; y < 4; ++y)
#pragma unroll
                for (int x = 0; x < 8; ++x) acc[y][x] += av[y] * bv[x];
        }
        __syncthreads();
    }

#pragma unroll
    for (int y = 0; y < 4; ++y) {
        const int m = m0 + tm * 4 + y;
#pragma unroll
        for (int g = 0; g < 2; ++g) {
            int n = n0 + g * 64 + tn * 4;
            float4 v;
            v.x = acc[y][g * 4 + 0];
            v.y = acc[y][g * 4 + 1];
            v.z = acc[y][g * 4 + 2];
            v.w = acc[y][g * 4 + 3];
            float* dst;
            if constexpr (MODE == 0) {
                v.x += bias[n + 0];
                v.y += bias[n + 1];
                v.z += bias[n + 2];
                v.w += bias[n + 3];
                dst = (n < DD) ? (O0 + (size_t)m * DD + n) : (O1 + (size_t)m * DD + (n - DD));
            } else {
                dst = (n < GG) ? (O0 + (size_t)m * GG + n) : (O1 + (size_t)m * GG + (n - GG));
            }
            *(float4*)dst = v;
        }
    }
}

// ---------------------------------------------------------------------------
// half-block (128-lane) candidate scorer, wave-reduced to lanes (tid&63)==0
// ---------------------------------------------------------------------------
__device__ __forceinline__ float half_dot(const float* __restrict__ ar,
                                          const float* __restrict__ br,
                                          const float* __restrict__ cb,
                                          const float* __restrict__ cl,
                                          const float* __restrict__ cr,
                                          const float* __restrict__ q, int lane) {
    float part = 0.f;
#pragma unroll
    for (int d = lane; d < DD; d += 128) {
        float gi = ar[d] + br[d] + cb[d];
        float gfl = ar[DD + d] + br[DD + d] + cb[DD + d];
        float gfr = ar[2 * DD + d] + br[2 * DD + d] + cb[2 * DD + d];
        float gu = ar[3 * DD + d] + br[3 * DD + d] + cb[3 * DD + d];
        float go = ar[4 * DD + d] + br[4 * DD + d] + cb[4 * DD + d];
        float nc = cl[d] * sigm(gfl + 1.f) + cr[d] * sigm(gfr + 1.f) + tanhf(gu) * sigm(gi);
        part += sigm(go) * tanhf(nc) * q[d];
    }
#pragma unroll
    for (int off = 32; off; off >>= 1) part += __shfl_down(part, off);
    return part;
}

// gate pair (normal cached loads — dispatch boundaries provide coherence)
__device__ __forceinline__ void gate2n(const float* __restrict__ ar,
                                       const float* __restrict__ br,
                                       const float* __restrict__ cb,
                                       const float* __restrict__ cl,
                                       const float* __restrict__ cr, int d,
                                       float nh[2], float nc[2]) {
    float2 A0 = *(const float2*)(ar + d),          B0 = *(const float2*)(br + d);
    float2 A1 = *(const float2*)(ar + DD + d),     B1 = *(const float2*)(br + DD + d);
    float2 A2 = *(const float2*)(ar + 2 * DD + d), B2 = *(const float2*)(br + 2 * DD + d);
    float2 A3 = *(const float2*)(ar + 3 * DD + d), B3 = *(const float2*)(br + 3 * DD + d);
    float2 A4 = *(const float2*)(ar + 4 * DD + d), B4 = *(const float2*)(br + 4 * DD + d);
    float2 C0 = *(const float2*)(cb + d);
    float2 C1 = *(const float2*)(cb + DD + d);
    float2 C2 = *(const float2*)(cb + 2 * DD + d);
    float2 C3 = *(const float2*)(cb + 3 * DD + d);
    float2 C4 = *(const float2*)(cb + 4 * DD + d);
    float2 CL = *(const float2*)(cl + d);
    float2 CR = *(const float2*)(cr + d);
    float gi0 = A0.x + B0.x + C0.x, gi1 = A0.y + B0.y + C0.y;
    float gfl0 = A1.x + B1.x + C1.x, gfl1 = A1.y + B1.y + C1.y;
    float gfr0 = A2.x + B2.x + C2.x, gfr1 = A2.y + B2.y + C2.y;
    float gu0 = A3.x + B3.x + C3.x, gu1 = A3.y + B3.y + C3.y;
    float go0 = A4.x + B4.x + C4.x, go1 = A4.y + B4.y + C4.y;
    nc[0] = CL.x * sigm(gfl0 + 1.f) + CR.x * sigm(gfr0 + 1.f) + tanhf(gu0) * sigm(gi0);
    nc[1] = CL.y * sigm(gfl1 + 1.f) + CR.y * sigm(gfr1 + 1.f) + tanhf(gu1) * sigm(gi1);
    nh[0] = sigm(go0) * tanhf(nc[0]);
    nh[1] = sigm(go1) * tanhf(nc[1]);
}

// ---------------------------------------------------------------------------
// initial scores: grid (12, 64); each block scores 2 candidates (half-block)
// ---------------------------------------------------------------------------
__global__ __launch_bounds__(256) void scoreall_k(const float* __restrict__ acache,
                                                  const float* __restrict__ bcache,
                                                  const float* __restrict__ cbuf,
                                                  const float* __restrict__ compb,
                                                  const float* __restrict__ q,
                                                  float* __restrict__ scores_g) {
    __shared__ float red_s[4];
    const int tid = threadIdx.x;
    const int b = blockIdx.y;
    const int p = blockIdx.x * 2 + (tid >> 7);
    const bool valid = p < NSTEP;
    float w = 0.f;
    if (valid) {
        w = half_dot(acache + (size_t)(b * LL + p) * GG,
                     bcache + (size_t)(b * LL + p + 1) * GG, compb,
                     cbuf + (size_t)(b * LL + p) * DD,
                     cbuf + (size_t)(b * LL + p + 1) * DD, q, tid & 127);
    }
    if ((tid & 63) == 0) red_s[tid >> 6] = w;
    __syncthreads();
    if ((tid == 0 || tid == 128) && valid) {
        int base = tid >> 6;
        scores_g[b * NSTEP + p] = red_s[base] + red_s[base + 1];
    }
}

// ---------------------------------------------------------------------------
// stepA: 64 blocks (one per batch). rescore <=2 affected candidates -> argmax
// -> merge gates -> hm[i]/hout/cbuf/msel; shift per-batch state (global).
// ---------------------------------------------------------------------------
__global__ __launch_bounds__(256) void stepA_k(
    int i, const int* __restrict__ length, float* __restrict__ cbuf,
    const float* __restrict__ acache, const float* __restrict__ bcache,
    float* __restrict__ hm, float* __restrict__ hout, float* __restrict__ scores_g,
    int* __restrict__ seq_g, int* __restrict__ kp_g, int* __restrict__ msel,
    const float* __restrict__ compb, const float* __restrict__ q, float* __restrict__ out) {
    __shared__ float red_s[4];
    __shared__ float sc_l[32];
    __shared__ int seq_l[32];
    __shared__ int k_sh;
    const int tid = threadIdx.x;
    const int b = blockIdx.x;
    const int lane7 = tid & 127;
    const int lenb = length[b];
    const int ncand = NSTEP - i;

    if (i == 0) {
        if (tid < LL) seq_l[tid] = tid;
    } else {
        if (tid < LL - i) seq_l[tid] = seq_g[b * 32 + tid];
    }
    if (tid < ncand) sc_l[tid] = scores_g[b * NSTEP + tid];
    __syncthreads();
    const int kp = (i > 0) ? kp_g[b] : 0;

    if (i > 0 && i < lenb) {  // rescore candidates kp-1, kp (half-block each)
        int p = (tid < 128) ? (kp - 1) : kp;
        bool valid = (p >= 0) && (p < ncand);
        float w = 0.f;
        if (valid) {
            int sl = seq_l[p], sr = seq_l[p + 1];
            const float* ar = acache + (size_t)(b * LL + sl) * GG;
            const float* br = bcache + (size_t)(b * LL + sr) * GG;
            const float* cl = cbuf + (size_t)(b * LL + sl) * DD;
            const float* cr = cbuf + (size_t)(b * LL + sr) * DD;
#pragma unroll
            for (int pass = 0; pass < 2; ++pass) {
                int d = pass * 256 + lane7 * 2;
                float nh[2], nc[2];
                gate2n(ar, br, compb, cl, cr, d, nh, nc);
                float2 Q = *(const float2*)(q + d);
                w += nh[0] * Q.x + nh[1] * Q.y;
            }
#pragma unroll
            for (int off = 32; off; off >>= 1) w += __shfl_down(w, off);
        }
        if ((tid & 63) == 0) red_s[tid >> 6] = w;
        __syncthreads();
        if (tid == 0) {
            if (kp - 1 >= 0) sc_l[kp - 1] = red_s[0] + red_s[1];
            if (kp < ncand) sc_l[kp] = red_s[2] + red_s[3];
        }
        __syncthreads();
    }

    if (i + 1 < lenb) {
        if (tid == 0) {
            const int vmax = lenb - i - 2;
            int k = 0;
            float best = sc_l[0];
            for (int pp = 1; pp <= vmax; ++pp)
                if (sc_l[pp] > best) { best = sc_l[pp]; k = pp; }
            k_sh = k;
        }
        __syncthreads();
        const int k = k_sh;
        const int sl = seq_l[k], sr = seq_l[k + 1];
        const float* ar = acache + (size_t)(b * LL + sl) * GG;
        const float* br = bcache + (size_t)(b * LL + sr) * GG;
        const float* cl = cbuf + (size_t)(b * LL + sl) * DD;
        const float* cr = cbuf + (size_t)(b * LL + sr) * DD;
        {
            const int d = 2 * tid;
            float nh[2], nc[2];
            gate2n(ar, br, compb, cl, cr, d, nh, nc);
            *(float2*)(cbuf + (size_t)(b * LL + sl) * DD + d) = make_float2(nc[0], nc[1]);
            *(float2*)(hout + (size_t)b * DD + d) = make_float2(nh[0], nh[1]);
            *(float2*)(hm + ((size_t)i * BB + b) * DD + d) = make_float2(nh[0], nh[1]);
            if (i == NSTEP - 1)
                *(float2*)(out + (size_t)b * DD + d) = make_float2(nh[0], nh[1]);
        }
        float sv = (tid + 1 < ncand) ? sc_l[tid + 1] : 0.f;
        int qv = (tid + 1 < LL - i) ? seq_l[tid + 1] : 0;
        __syncthreads();
        if (tid >= k + 1 && tid <= ncand - 2) sc_l[tid] = sv;
        if (tid >= k + 1 && tid <= LL - i - 2) seq_l[tid] = qv;
        // write back per-batch state
        if (tid < ncand - 1) scores_g[b * NSTEP + tid] = sc_l[tid];
        if (tid < LL - i - 1) seq_g[b * 32 + tid] = seq_l[tid];
        if (tid == 0) { kp_g[b] = k; msel[b] = sl; }
    } else {
        const int d = 2 * tid;
        float2 v = *(const float2*)(hout + (size_t)b * DD + d);
        *(float2*)(hm + ((size_t)i * BB + b) * DD + d) = v;
        if (i == NSTEP - 1) *(float2*)(out + (size_t)b * DD + d) = v;
    }
}

// ---------------------------------------------------------------------------
// stepB: 160 blocks; a/b rows for the merged item of each batch.
// R10's best-measured body (64x32 tile, full K, 4x2 microtile, 256 threads),
// with normal loads/stores (dispatch boundary = coherence).
// ---------------------------------------------------------------------------
__global__ __launch_bounds__(256) void stepB_k(
    int i, const float* __restrict__ hm, const int* __restrict__ msel,
    const float* __restrict__ comp_W, float* __restrict__ acache,
    float* __restrict__ bcache) {
    __shared__ float As[128][68];
    __shared__ float Bs[128][36];
    __shared__ int msel_s[BB];
    const int tid = threadIdx.x;
    const int bid = blockIdx.x;
    const int sar = tid & 63, sak = tid >> 6;   // A staging: row=lane, 4 k-slices
    const int swn = tid & 31, swk = tid >> 5;   // W staging: row=lane%32, 8 k-slices
    const int tn = tid & 15, tm = tid >> 4;     // compute: 64m x 32n, 4x2

    if (tid < BB) msel_s[tid] = msel[tid];
    {
        int n = bid * 32 + swn;
        const float* wrow = (n < GG) ? (comp_W + (size_t)n * (2 * DD))
                                     : (comp_W + (size_t)(n - GG) * (2 * DD) + DD);
        const float* arow = hm + (size_t)i * BB * DD + (size_t)sar * DD;
        float acc[4][2];
#pragma unroll
        for (int y = 0; y < 4; ++y) { acc[y][0] = 0.f; acc[y][1] = 0.f; }
        float4 ra[8], rw[4];
#pragma unroll
        for (int j = 0; j < 8; ++j) ra[j] = *(const float4*)(arow + sak * 32 + j * 4);
#pragma unroll
        for (int j = 0; j < 4; ++j) rw[j] = *(const float4*)(wrow + swk * 16 + j * 4);
#pragma unroll 1
        for (int c = 0; c < 4; ++c) {
            __syncthreads();
#pragma unroll
            for (int j = 0; j < 8; ++j) {   // A: 64 rows x 128 k (row=lane, free)
                int kl = sak * 32 + j * 4;
                As[kl + 0][sar] = ra[j].x;
                As[kl + 1][sar] = ra[j].y;
                As[kl + 2][sar] = ra[j].z;
                As[kl + 3][sar] = ra[j].w;
            }
#pragma unroll
            for (int j = 0; j < 4; ++j) {   // W: 32 rows x 128 k
                int kl = swk * 16 + j * 4;
                Bs[kl + 0][swn] = rw[j].x;
                Bs[kl + 1][swn] = rw[j].y;
                Bs[kl + 2][swn] = rw[j].z;
                Bs[kl + 3][swn] = rw[j].w;
            }
            if (c < 3) {  // prefetch next chunk over compute
                int kb = (c + 1) * 128;
#pragma unroll
                for (int j = 0; j < 8; ++j)
                    ra[j] = *(const float4*)(arow + kb + sak * 32 + j * 4);
#pragma unroll
                for (int j = 0; j < 4; ++j)
                    rw[j] = *(const float4*)(wrow + kb + swk * 16 + j * 4);
            }
            __syncthreads();
#pragma unroll 8
            for (int k = 0; k < 128; ++k) {
                float4 a = *(const float4*)&As[k][tm * 4];
                float2 w = *(const float2*)&Bs[k][tn * 2];
                acc[0][0] += a.x * w.x; acc[0][1] += a.x * w.y;
                acc[1][0] += a.y * w.x; acc[1][1] += a.y * w.y;
                acc[2][0] += a.z * w.x; acc[2][1] += a.z * w.y;
                acc[3][0] += a.w * w.x; acc[3][1] += a.w * w.y;
            }
        }
        const int n0 = bid * 32 + tn * 2;
#pragma unroll
        for (int y = 0; y < 4; ++y) {
            int m = tm * 4 + y;
            size_t row = (size_t)(m * LL + msel_s[m]);
            float* dst = (n0 < GG) ? (acache + row * GG + n0)
                                   : (bcache + row * GG + (n0 - GG));
            *(float2*)dst = make_float2(acc[y][0], acc[y][1]);
        }
    }
}

// ---------------------------------------------------------------------------
extern "C" void kernel_launch(void* const* d_in, const int* in_sizes, int n_in, void* d_out,
                              int out_size, void* d_ws, size_t ws_size, hipStream_t stream) {
    const float* inp = (const float*)d_in[0];
    const int* length = (const int*)d_in[1];
    const float* word_W = (const float*)d_in[2];
    const float* word_b = (const float*)d_in[3];
    const float* comp_W = (const float*)d_in[4];
    const float* comp_b = (const float*)d_in[5];
    const float* comp_q = (const float*)d_in[6];
    float* out = (float*)d_out;

    float* ws = (float*)d_ws;
    size_t off = 0;
    float* hbuf = ws + off;   off += (size_t)BB * LL * DD;
    float* cbuf = ws + off;   off += (size_t)BB * LL * DD;
    float* acache = ws + off; off += (size_t)BB * LL * GG;
    float* bcache = ws + off; off += (size_t)BB * LL * GG;
    float* hm = ws + off;     off += (size_t)NSTEP * BB * DD;
    float* hout = ws + off;   off += (size_t)BB * DD;
    float* scores = ws + off; off += 2048;
    int* seq_g = (int*)(ws + off); off += BB * 32;
    int* kp_g = (int*)(ws + off);  off += 64;
    int* msel = (int*)(ws + off);  off += 64;
    (void)ws_size; (void)in_sizes; (void)n_in; (void)out_size;

    // word projection: h,c = split(inp @ word_W.T + word_b)
    gemm64<0><<<dim3(8, 24), 256, 0, stream>>>(inp, word_W, word_b, hbuf, cbuf);

    // a/b caches for all 1536 items
    gemm64<1><<<dim3(40, 24), 256, 0, stream>>>(hbuf, comp_W, nullptr, acache, bcache);

    // initial candidate scores
    scoreall_k<<<dim3(12, 64), 256, 0, stream>>>(acache, bcache, cbuf, comp_b, comp_q, scores);

    // 23 merge steps: A (select+merge) then B (a/b GEMM for merged rows)
    for (int i = 0; i < NSTEP; ++i) {
        stepA_k<<<BB, 256, 0, stream>>>(i, length, cbuf, acache, bcache, hm, hout, scores,
                                        seq_g, kp_g, msel, comp_b, comp_q, out);
        if (i < NSTEP - 1) {
            stepB_k<<<NTILES, 256, 0, stream>>>(i, hm, msel, comp_W, acache, bcache);
        }
    }
}

// Round 13
// 754.682 us; speedup vs baseline: 1.5512x; 1.0210x over previous
//
#include <hip/hip_runtime.h>
#include <math.h>

// Problem constants
#define BB 64
#define LL 24
#define DD 512
#define GG 2560        // 5*H
#define NSTEP 23       // LL-1
#define NTILES 160     // stepB n-tiles: 5120/32, full-K per tile

__device__ __forceinline__ float sigm(float x) { return 1.0f / (1.0f + __expf(-x)); }

// ---------------------------------------------------------------------------
// fp32 GEMM, 128x128 tile, 8x8 microtile, conflict-free (R2 layout).
// C[m][n] = sum_k A[m][k]*W[n][k]. MODE 1 = AB0 (W = comp_W halves at n=2560).
// Inner loop: 4 LDS b128 per 64 FMA (2x the VALU density of the 64x128 tile).
// ---------------------------------------------------------------------------
__global__ __launch_bounds__(256) void gemm_big(const float* __restrict__ A,
                                                const float* __restrict__ Wt,
                                                float* __restrict__ O0,
                                                float* __restrict__ O1) {
    __shared__ float As[16][132];
    __shared__ float Bs[16][132];
    const int tid = threadIdx.x;
    const int n0 = blockIdx.x * 128;
    const int m0 = blockIdx.y * 128;
    const int tn = tid & 15;
    const int tm = tid >> 4;

    float acc[8][8];
#pragma unroll
    for (int y = 0; y < 8; ++y)
#pragma unroll
        for (int x = 0; x < 8; ++x) acc[y][x] = 0.f;

    for (int kt = 0; kt < 512; kt += 16) {
#pragma unroll
        for (int ii = 0; ii < 2; ++ii) {
            int idx = tid + ii * 256;
            int r = idx >> 2, c4 = idx & 3;
            float4 v = *(const float4*)(A + (size_t)(m0 + r) * DD + kt + c4 * 4);
            As[c4 * 4 + 0][r] = v.x;
            As[c4 * 4 + 1][r] = v.y;
            As[c4 * 4 + 2][r] = v.z;
            As[c4 * 4 + 3][r] = v.w;
        }
#pragma unroll
        for (int ii = 0; ii < 2; ++ii) {
            int idx = tid + ii * 256;
            int r = idx >> 2, c4 = idx & 3;
            int n = n0 + r;
            const float* wrow = (n < GG) ? (Wt + (size_t)n * (2 * DD))
                                         : (Wt + (size_t)(n - GG) * (2 * DD) + DD);
            float4 v = *(const float4*)(wrow + kt + c4 * 4);
            Bs[c4 * 4 + 0][r] = v.x;
            Bs[c4 * 4 + 1][r] = v.y;
            Bs[c4 * 4 + 2][r] = v.z;
            Bs[c4 * 4 + 3][r] = v.w;
        }
        __syncthreads();
#pragma unroll
        for (int k = 0; k < 16; ++k) {
            float4 a0 = *(const float4*)&As[k][tm * 8];
            float4 a1 = *(const float4*)&As[k][tm * 8 + 4];
            float4 b0 = *(const float4*)&Bs[k][tn * 4];
            float4 b1 = *(const float4*)&Bs[k][64 + tn * 4];
            float av[8] = {a0.x, a0.y, a0.z, a0.w, a1.x, a1.y, a1.z, a1.w};
            float bv[8] = {b0.x, b0.y, b0.z, b0.w, b1.x, b1.y, b1.z, b1.w};
#pragma unroll
            for (int y = 0; y < 8; ++y)
#pragma unroll
                for (int x = 0; x < 8; ++x) acc[y][x] += av[y] * bv[x];
        }
        __syncthreads();
    }

#pragma unroll
    for (int y = 0; y < 8; ++y) {
        const int m = m0 + tm * 8 + y;
#pragma unroll
        for (int g = 0; g < 2; ++g) {
            int n = n0 + g * 64 + tn * 4;
            float4 v;
            v.x = acc[y][g * 4 + 0];
            v.y = acc[y][g * 4 + 1];
            v.z = acc[y][g * 4 + 2];
            v.w = acc[y][g * 4 + 3];
            float* dst = (n < GG) ? (O0 + (size_t)m * GG + n)
                                  : (O1 + (size_t)m * GG + (n - GG));
            *(float4*)dst = v;
        }
    }
}

// ---------------------------------------------------------------------------
// fp32 GEMM, 64x128 tile — kept for the word projection (more blocks at
// small M x N). MODE 0: W 1024x512 row-major, +bias, out h|c split at n=512.
// ---------------------------------------------------------------------------
__global__ __launch_bounds__(256) void gemm64w(const float* __restrict__ A,
                                               const float* __restrict__ Wt,
                                               const float* __restrict__ bias,
                                               float* __restrict__ O0,
                                               float* __restrict__ O1) {
    __shared__ float As[16][68];
    __shared__ float Bs[16][132];
    const int tid = threadIdx.x;
    const int n0 = blockIdx.x * 128;
    const int m0 = blockIdx.y * 64;
    const int tn = tid & 15;
    const int tm = tid >> 4;

    float acc[4][8];
#pragma unroll
    for (int y = 0; y < 4; ++y)
#pragma unroll
        for (int x = 0; x < 8; ++x) acc[y][x] = 0.f;

    for (int kt = 0; kt < 512; kt += 16) {
        {
            int r = tid >> 2, c4 = tid & 3;
            float4 v = *(const float4*)(A + (size_t)(m0 + r) * DD + kt + c4 * 4);
            As[c4 * 4 + 0][r] = v.x;
            As[c4 * 4 + 1][r] = v.y;
            As[c4 * 4 + 2][r] = v.z;
            As[c4 * 4 + 3][r] = v.w;
        }
#pragma unroll
        for (int ii = 0; ii < 2; ++ii) {
            int idx = tid + ii * 256;
            int r = idx >> 2, c4 = idx & 3;
            float4 v = *(const float4*)(Wt + (size_t)(n0 + r) * DD + kt + c4 * 4);
            Bs[c4 * 4 + 0][r] = v.x;
            Bs[c4 * 4 + 1][r] = v.y;
            Bs[c4 * 4 + 2][r] = v.z;
            Bs[c4 * 4 + 3][r] = v.w;
        }
        __syncthreads();
#pragma unroll
        for (int k = 0; k < 16; ++k) {
            float4 a = *(const float4*)&As[k][tm * 4];
            float4 b0 = *(const float4*)&Bs[k][tn * 4];
            float4 b1 = *(const float4*)&Bs[k][64 + tn * 4];
            float av[4] = {a.x, a.y, a.z, a.w};
            float bv[8] = {b0.x, b0.y, b0.z, b0.w, b1.x, b1.y, b1.z, b1.w};
#pragma unroll
            for (int y = 0; y < 4; ++y)
#pragma unroll
                for (int x = 0; x < 8; ++x) acc[y][x] += av[y] * bv[x];
        }
        __syncthreads();
    }

#pragma unroll
    for (int y = 0; y < 4; ++y) {
        const int m = m0 + tm * 4 + y;
#pragma unroll
        for (int g = 0; g < 2; ++g) {
            int n = n0 + g * 64 + tn * 4;
            float4 v;
            v.x = acc[y][g * 4 + 0] + bias[n + 0];
            v.y = acc[y][g * 4 + 1] + bias[n + 1];
            v.z = acc[y][g * 4 + 2] + bias[n + 2];
            v.w = acc[y][g * 4 + 3] + bias[n + 3];
            float* dst = (n < DD) ? (O0 + (size_t)m * DD + n)
                                  : (O1 + (size_t)m * DD + (n - DD));
            *(float4*)dst = v;
        }
    }
}

// ---------------------------------------------------------------------------
// half-block (128-lane) candidate scorer, wave-reduced to lanes (tid&63)==0
// ---------------------------------------------------------------------------
__device__ __forceinline__ float half_dot(const float* __restrict__ ar,
                                          const float* __restrict__ br,
                                          const float* __restrict__ cb,
                                          const float* __restrict__ cl,
                                          const float* __restrict__ cr,
                                          const float* __restrict__ q, int lane) {
    float part = 0.f;
#pragma unroll
    for (int d = lane; d < DD; d += 128) {
        float gi = ar[d] + br[d] + cb[d];
        float gfl = ar[DD + d] + br[DD + d] + cb[DD + d];
        float gfr = ar[2 * DD + d] + br[2 * DD + d] + cb[2 * DD + d];
        float gu = ar[3 * DD + d] + br[3 * DD + d] + cb[3 * DD + d];
        float go = ar[4 * DD + d] + br[4 * DD + d] + cb[4 * DD + d];
        float nc = cl[d] * sigm(gfl + 1.f) + cr[d] * sigm(gfr + 1.f) + tanhf(gu) * sigm(gi);
        part += sigm(go) * tanhf(nc) * q[d];
    }
#pragma unroll
    for (int off = 32; off; off >>= 1) part += __shfl_down(part, off);
    return part;
}

// gate pair (normal cached loads — dispatch boundaries provide coherence)
__device__ __forceinline__ void gate2n(const float* __restrict__ ar,
                                       const float* __restrict__ br,
                                       const float* __restrict__ cb,
                                       const float* __restrict__ cl,
                                       const float* __restrict__ cr, int d,
                                       float nh[2], float nc[2]) {
    float2 A0 = *(const float2*)(ar + d),          B0 = *(const float2*)(br + d);
    float2 A1 = *(const float2*)(ar + DD + d),     B1 = *(const float2*)(br + DD + d);
    float2 A2 = *(const float2*)(ar + 2 * DD + d), B2 = *(const float2*)(br + 2 * DD + d);
    float2 A3 = *(const float2*)(ar + 3 * DD + d), B3 = *(const float2*)(br + 3 * DD + d);
    float2 A4 = *(const float2*)(ar + 4 * DD + d), B4 = *(const float2*)(br + 4 * DD + d);
    float2 C0 = *(const float2*)(cb + d);
    float2 C1 = *(const float2*)(cb + DD + d);
    float2 C2 = *(const float2*)(cb + 2 * DD + d);
    float2 C3 = *(const float2*)(cb + 3 * DD + d);
    float2 C4 = *(const float2*)(cb + 4 * DD + d);
    float2 CL = *(const float2*)(cl + d);
    float2 CR = *(const float2*)(cr + d);
    float gi0 = A0.x + B0.x + C0.x, gi1 = A0.y + B0.y + C0.y;
    float gfl0 = A1.x + B1.x + C1.x, gfl1 = A1.y + B1.y + C1.y;
    float gfr0 = A2.x + B2.x + C2.x, gfr1 = A2.y + B2.y + C2.y;
    float gu0 = A3.x + B3.x + C3.x, gu1 = A3.y + B3.y + C3.y;
    float go0 = A4.x + B4.x + C4.x, go1 = A4.y + B4.y + C4.y;
    nc[0] = CL.x * sigm(gfl0 + 1.f) + CR.x * sigm(gfr0 + 1.f) + tanhf(gu0) * sigm(gi0);
    nc[1] = CL.y * sigm(gfl1 + 1.f) + CR.y * sigm(gfr1 + 1.f) + tanhf(gu1) * sigm(gi1);
    nh[0] = sigm(go0) * tanhf(nc[0]);
    nh[1] = sigm(go1) * tanhf(nc[1]);
}

// ---------------------------------------------------------------------------
// initial scores: grid (12, 64); each block scores 2 candidates (half-block)
// ---------------------------------------------------------------------------
__global__ __launch_bounds__(256) void scoreall_k(const float* __restrict__ acache,
                                                  const float* __restrict__ bcache,
                                                  const float* __restrict__ cbuf,
                                                  const float* __restrict__ compb,
                                                  const float* __restrict__ q,
                                                  float* __restrict__ scores_g) {
    __shared__ float red_s[4];
    const int tid = threadIdx.x;
    const int b = blockIdx.y;
    const int p = blockIdx.x * 2 + (tid >> 7);
    const bool valid = p < NSTEP;
    float w = 0.f;
    if (valid) {
        w = half_dot(acache + (size_t)(b * LL + p) * GG,
                     bcache + (size_t)(b * LL + p + 1) * GG, compb,
                     cbuf + (size_t)(b * LL + p) * DD,
                     cbuf + (size_t)(b * LL + p + 1) * DD, q, tid & 127);
    }
    if ((tid & 63) == 0) red_s[tid >> 6] = w;
    __syncthreads();
    if ((tid == 0 || tid == 128) && valid) {
        int base = tid >> 6;
        scores_g[b * NSTEP + p] = red_s[base] + red_s[base + 1];
    }
}

// ---------------------------------------------------------------------------
// stepA: 64 blocks (one per batch). rescore <=2 affected candidates -> argmax
// -> merge gates -> hout/cbuf/msel; shift per-batch state (global).
// ---------------------------------------------------------------------------
__global__ __launch_bounds__(256) void stepA_k(
    int i, const int* __restrict__ length, float* __restrict__ cbuf,
    const float* __restrict__ acache, const float* __restrict__ bcache,
    float* __restrict__ hout, float* __restrict__ scores_g,
    int* __restrict__ seq_g, int* __restrict__ kp_g, int* __restrict__ msel,
    const float* __restrict__ compb, const float* __restrict__ q, float* __restrict__ out) {
    __shared__ float red_s[4];
    __shared__ float sc_l[32];
    __shared__ int seq_l[32];
    __shared__ int k_sh;
    const int tid = threadIdx.x;
    const int b = blockIdx.x;
    const int lane7 = tid & 127;
    const int lenb = length[b];
    const int ncand = NSTEP - i;

    if (i == 0) {
        if (tid < LL) seq_l[tid] = tid;
    } else {
        if (tid < LL - i) seq_l[tid] = seq_g[b * 32 + tid];
    }
    if (tid < ncand) sc_l[tid] = scores_g[b * NSTEP + tid];
    __syncthreads();
    const int kp = (i > 0) ? kp_g[b] : 0;

    if (i > 0 && i < lenb) {  // rescore candidates kp-1, kp (half-block each)
        int p = (tid < 128) ? (kp - 1) : kp;
        bool valid = (p >= 0) && (p < ncand);
        float w = 0.f;
        if (valid) {
            int sl = seq_l[p], sr = seq_l[p + 1];
            const float* ar = acache + (size_t)(b * LL + sl) * GG;
            const float* br = bcache + (size_t)(b * LL + sr) * GG;
            const float* cl = cbuf + (size_t)(b * LL + sl) * DD;
            const float* cr = cbuf + (size_t)(b * LL + sr) * DD;
#pragma unroll
            for (int pass = 0; pass < 2; ++pass) {
                int d = pass * 256 + lane7 * 2;
                float nh[2], nc[2];
                gate2n(ar, br, compb, cl, cr, d, nh, nc);
                float2 Q = *(const float2*)(q + d);
                w += nh[0] * Q.x + nh[1] * Q.y;
            }
#pragma unroll
            for (int off = 32; off; off >>= 1) w += __shfl_down(w, off);
        }
        if ((tid & 63) == 0) red_s[tid >> 6] = w;
        __syncthreads();
        if (tid == 0) {
            if (kp - 1 >= 0) sc_l[kp - 1] = red_s[0] + red_s[1];
            if (kp < ncand) sc_l[kp] = red_s[2] + red_s[3];
        }
        __syncthreads();
    }

    if (i + 1 < lenb) {
        if (tid == 0) {
            const int vmax = lenb - i - 2;
            int k = 0;
            float best = sc_l[0];
            for (int pp = 1; pp <= vmax; ++pp)
                if (sc_l[pp] > best) { best = sc_l[pp]; k = pp; }
            k_sh = k;
        }
        __syncthreads();
        const int k = k_sh;
        const int sl = seq_l[k], sr = seq_l[k + 1];
        const float* ar = acache + (size_t)(b * LL + sl) * GG;
        const float* br = bcache + (size_t)(b * LL + sr) * GG;
        const float* cl = cbuf + (size_t)(b * LL + sl) * DD;
        const float* cr = cbuf + (size_t)(b * LL + sr) * DD;
        {
            const int d = 2 * tid;
            float nh[2], nc[2];
            gate2n(ar, br, compb, cl, cr, d, nh, nc);
            *(float2*)(cbuf + (size_t)(b * LL + sl) * DD + d) = make_float2(nc[0], nc[1]);
            *(float2*)(hout + (size_t)b * DD + d) = make_float2(nh[0], nh[1]);
            if (i == NSTEP - 1)
                *(float2*)(out + (size_t)b * DD + d) = make_float2(nh[0], nh[1]);
        }
        float sv = (tid + 1 < ncand) ? sc_l[tid + 1] : 0.f;
        int qv = (tid + 1 < LL - i) ? seq_l[tid + 1] : 0;
        __syncthreads();
        if (tid >= k + 1 && tid <= ncand - 2) sc_l[tid] = sv;
        if (tid >= k + 1 && tid <= LL - i - 2) seq_l[tid] = qv;
        if (tid < ncand - 1) scores_g[b * NSTEP + tid] = sc_l[tid];
        if (tid < LL - i - 1) seq_g[b * 32 + tid] = seq_l[tid];
        if (tid == 0) { kp_g[b] = k; msel[b] = sl; }
    } else if (i == NSTEP - 1) {
        const int d = 2 * tid;
        *(float2*)(out + (size_t)b * DD + d) = *(const float2*)(hout + (size_t)b * DD + d);
    }
}

// ---------------------------------------------------------------------------
// stepB: 160 blocks; a/b rows for the merged item of each batch. Reads hout
// directly (stepA(i) wrote it; dispatch order guarantees visibility).
// ---------------------------------------------------------------------------
__global__ __launch_bounds__(256) void stepB_k(
    const float* __restrict__ hout, const int* __restrict__ msel,
    const float* __restrict__ comp_W, float* __restrict__ acache,
    float* __restrict__ bcache) {
    __shared__ float As[128][68];
    __shared__ float Bs[128][36];
    __shared__ int msel_s[BB];
    const int tid = threadIdx.x;
    const int bid = blockIdx.x;
    const int sar = tid & 63, sak = tid >> 6;   // A staging: row=lane, 4 k-slices
    const int swn = tid & 31, swk = tid >> 5;   // W staging: row=lane%32, 8 k-slices
    const int tn = tid & 15, tm = tid >> 4;     // compute: 64m x 32n, 4x2

    if (tid < BB) msel_s[tid] = msel[tid];
    {
        int n = bid * 32 + swn;
        const float* wrow = (n < GG) ? (comp_W + (size_t)n * (2 * DD))
                                     : (comp_W + (size_t)(n - GG) * (2 * DD) + DD);
        const float* arow = hout + (size_t)sar * DD;
        float acc[4][2];
#pragma unroll
        for (int y = 0; y < 4; ++y) { acc[y][0] = 0.f; acc[y][1] = 0.f; }
        float4 ra[8], rw[4];
#pragma unroll
        for (int j = 0; j < 8; ++j) ra[j] = *(const float4*)(arow + sak * 32 + j * 4);
#pragma unroll
        for (int j = 0; j < 4; ++j) rw[j] = *(const float4*)(wrow + swk * 16 + j * 4);
#pragma unroll 1
        for (int c = 0; c < 4; ++c) {
            __syncthreads();
#pragma unroll
            for (int j = 0; j < 8; ++j) {   // A: 64 rows x 128 k (row=lane, free)
                int kl = sak * 32 + j * 4;
                As[kl + 0][sar] = ra[j].x;
                As[kl + 1][sar] = ra[j].y;
                As[kl + 2][sar] = ra[j].z;
                As[kl + 3][sar] = ra[j].w;
            }
#pragma unroll
            for (int j = 0; j < 4; ++j) {   // W: 32 rows x 128 k
                int kl = swk * 16 + j * 4;
                Bs[kl + 0][swn] = rw[j].x;
                Bs[kl + 1][swn] = rw[j].y;
                Bs[kl + 2][swn] = rw[j].z;
                Bs[kl + 3][swn] = rw[j].w;
            }
            if (c < 3) {  // prefetch next chunk over compute
                int kb = (c + 1) * 128;
#pragma unroll
                for (int j = 0; j < 8; ++j)
                    ra[j] = *(const float4*)(arow + kb + sak * 32 + j * 4);
#pragma unroll
                for (int j = 0; j < 4; ++j)
                    rw[j] = *(const float4*)(wrow + kb + swk * 16 + j * 4);
            }
            __syncthreads();
#pragma unroll 8
            for (int k = 0; k < 128; ++k) {
                float4 a = *(const float4*)&As[k][tm * 4];
                float2 w = *(const float2*)&Bs[k][tn * 2];
                acc[0][0] += a.x * w.x; acc[0][1] += a.x * w.y;
                acc[1][0] += a.y * w.x; acc[1][1] += a.y * w.y;
                acc[2][0] += a.z * w.x; acc[2][1] += a.z * w.y;
                acc[3][0] += a.w * w.x; acc[3][1] += a.w * w.y;
            }
        }
        const int n0 = bid * 32 + tn * 2;
#pragma unroll
        for (int y = 0; y < 4; ++y) {
            int m = tm * 4 + y;
            size_t row = (size_t)(m * LL + msel_s[m]);
            float* dst = (n0 < GG) ? (acache + row * GG + n0)
                                   : (bcache + row * GG + (n0 - GG));
            *(float2*)dst = make_float2(acc[y][0], acc[y][1]);
        }
    }
}

// ---------------------------------------------------------------------------
extern "C" void kernel_launch(void* const* d_in, const int* in_sizes, int n_in, void* d_out,
                              int out_size, void* d_ws, size_t ws_size, hipStream_t stream) {
    const float* inp = (const float*)d_in[0];
    const int* length = (const int*)d_in[1];
    const float* word_W = (const float*)d_in[2];
    const float* word_b = (const float*)d_in[3];
    const float* comp_W = (const float*)d_in[4];
    const float* comp_b = (const float*)d_in[5];
    const float* comp_q = (const float*)d_in[6];
    float* out = (float*)d_out;

    float* ws = (float*)d_ws;
    size_t off = 0;
    float* hbuf = ws + off;   off += (size_t)BB * LL * DD;
    float* cbuf = ws + off;   off += (size_t)BB * LL * DD;
    float* acache = ws + off; off += (size_t)BB * LL * GG;
    float* bcache = ws + off; off += (size_t)BB * LL * GG;
    float* hout = ws + off;   off += (size_t)BB * DD;
    float* scores = ws + off; off += 2048;
    int* seq_g = (int*)(ws + off); off += BB * 32;
    int* kp_g = (int*)(ws + off);  off += 64;
    int* msel = (int*)(ws + off);  off += 64;
    (void)ws_size; (void)in_sizes; (void)n_in; (void)out_size;

    // word projection: h,c = split(inp @ word_W.T + word_b)
    gemm64w<<<dim3(8, 24), 256, 0, stream>>>(inp, word_W, word_b, hbuf, cbuf);

    // a/b caches for all 1536 items (128x128 tile, 8x8 microtile)
    gemm_big<<<dim3(40, 12), 256, 0, stream>>>(hbuf, comp_W, acache, bcache);

    // initial candidate scores
    scoreall_k<<<dim3(12, 64), 256, 0, stream>>>(acache, bcache, cbuf, comp_b, comp_q, scores);

    // 23 merge steps: A (select+merge) then B (a/b GEMM for merged rows)
    for (int i = 0; i < NSTEP; ++i) {
        stepA_k<<<BB, 256, 0, stream>>>(i, length, cbuf, acache, bcache, hout, scores,
                                        seq_g, kp_g, msel, comp_b, comp_q, out);
        if (i < NSTEP - 1) {
            stepB_k<<<NTILES, 256, 0, stream>>>(hout, msel, comp_W, acache, bcache);
        }
    }
}